// Round 11
// baseline (110.311 us; speedup 1.0000x reference)
//
#include <hip/hip_runtime.h>
#include <math.h>

#define BS   4
#define V    4096
#define NB   50
#define IC   64
#define OC   64
#define SUP  4
#define WCOL 320
#define WT_STRIDE 72     // shorts; 144B row -> 2-way LDS bank aliasing (free)

typedef float    f32x4 __attribute__((ext_vector_type(4)));
typedef short    s16x8 __attribute__((ext_vector_type(8)));
typedef _Float16 h16x2 __attribute__((ext_vector_type(2)));

__device__ inline unsigned short bf16r(float f) {          // RNE f32->bf16
    unsigned u = __builtin_bit_cast(unsigned, f);
    u += 0x7FFFu + ((u >> 16) & 1u);
    return (unsigned short)(u >> 16);
}
__device__ inline float fdot2acc(h16x2 a, h16x2 b, float c) {
#if __has_builtin(__builtin_amdgcn_fdot2)
    return __builtin_amdgcn_fdot2(a, b, c, false);   // v_dot2_f32_f16
#else
    return c + (float)a.x * (float)b.x + (float)a.y * (float)b.y;
#endif
}

// ---------------------------------------------------------------------------
// Kernel 1 (MFMA): feature_out = fm @ W + bias.
//   out[row*64 + c]          = feature_out[row][c]          (center -> d_out)
//   fo_s[(row*64 + c)*4 + s] = f16(feature_out[row][64+s*64+c])
// ---------------------------------------------------------------------------
__global__ __launch_bounds__(256) void feat_kernel(
    const float* __restrict__ fm,    // (16384, 64)
    const float* __restrict__ W,     // (64, 320)
    const float* __restrict__ bias,  // (320,)
    float* __restrict__ out,         // (16384, 64)  center slice
    unsigned short* __restrict__ fo_s)  // f16
{
    __shared__ unsigned short wt[WCOL * WT_STRIDE];  // wt[col][k], 45 KB
    const int t = threadIdx.x;

#pragma unroll
    for (int i = 0; i < 20; ++i) {
        const int idx4 = t + i * 256;
        const int e    = idx4 * 4;
        const int k    = e / WCOL;
        const int col  = e - k * WCOL;
        const float4 v = reinterpret_cast<const float4*>(W)[idx4];
        wt[(col + 0) * WT_STRIDE + k] = bf16r(v.x);
        wt[(col + 1) * WT_STRIDE + k] = bf16r(v.y);
        wt[(col + 2) * WT_STRIDE + k] = bf16r(v.z);
        wt[(col + 3) * WT_STRIDE + k] = bf16r(v.w);
    }
    __syncthreads();

    const int w   = t >> 6;
    const int l   = t & 63;
    const int rlo = l & 15;
    const int kg  = l >> 4;
    const int row = blockIdx.x * 64 + w * 16 + rlo;

    const float* fr = &fm[row * IC + kg * 8];
    s16x8 a0, a1;
#pragma unroll
    for (int e = 0; e < 8; ++e) {
        a0[e] = (short)bf16r(fr[e]);
        a1[e] = (short)bf16r(fr[32 + e]);
    }

    const int drow0 = blockIdx.x * 64 + w * 16 + kg * 4;
#pragma unroll
    for (int ct = 0; ct < 20; ++ct) {
        const int col = ct * 16 + rlo;
        const s16x8 b0 = *reinterpret_cast<const s16x8*>(&wt[col * WT_STRIDE + kg * 8]);
        const s16x8 b1 = *reinterpret_cast<const s16x8*>(&wt[col * WT_STRIDE + 32 + kg * 8]);
        f32x4 acc = {0.f, 0.f, 0.f, 0.f};
        acc = __builtin_amdgcn_mfma_f32_16x16x32_bf16(a0, b0, acc, 0, 0, 0);
        acc = __builtin_amdgcn_mfma_f32_16x16x32_bf16(a1, b1, acc, 0, 0, 0);
        const float bv = bias[col];
        if (ct < 4) {
#pragma unroll
            for (int r = 0; r < 4; ++r)
                out[(drow0 + r) * OC + col] = acc[r] + bv;
        } else {
            const int cc = (col - OC) & 63;
            const int s  = (col - OC) >> 6;
#pragma unroll
            for (int r = 0; r < 4; ++r)
                fo_s[((drow0 + r) * OC + cc) * SUP + s] =
                    __builtin_bit_cast(unsigned short, (_Float16)(acc[r] + bv));
        }
    }
}

// ---------------------------------------------------------------------------
// Kernel 2 (prep): per (row, j) one uint4:
//   { f16(dx)|f16(dx), f16(dy)|f16(dy), f16(dz)|f16(w), idx<<9 }
// ---------------------------------------------------------------------------
__global__ __launch_bounds__(256) void prep_kernel(
    const int*   __restrict__ nidx,   // (BS, V, 50)
    const float* __restrict__ verts,  // (BS, V, 3)
    const float* __restrict__ nval,   // (BS, V, 50)
    uint4* __restrict__ tbl)          // (16384, 50)
{
    const int wv  = threadIdx.x >> 6;
    const int c   = threadIdx.x & 63;
    const int row = blockIdx.x * 4 + wv;
    const int b   = row >> 12;

    const float nv = (c < NB) ? nval[(size_t)row * NB + c] : 0.f;
    float ss = nv * nv;
#pragma unroll
    for (int o = 32; o > 0; o >>= 1) ss += __shfl_xor(ss, o);
    const float wn = nv * (1.f / fmaxf(sqrtf(ss), 1e-12f));

    if (c < NB) {
        const int idx = nidx[(size_t)row * NB + c];
        const float* vn = &verts[(size_t)(b * V + idx) * 3];
        const float* vc = &verts[(size_t)row * 3];
        float dx = vn[0] - vc[0], dy = vn[1] - vc[1], dz = vn[2] - vc[2];
        const float inv = 1.f / fmaxf(sqrtf(dx * dx + dy * dy + dz * dz), 1e-12f);
        dx *= inv; dy *= inv; dz *= inv;
        h16x2 xx = { (_Float16)dx, (_Float16)dx };
        h16x2 yy = { (_Float16)dy, (_Float16)dy };
        h16x2 zw = { (_Float16)dz, (_Float16)wn };
        uint4 u;
        u.x = __builtin_bit_cast(unsigned, xx);
        u.y = __builtin_bit_cast(unsigned, yy);
        u.z = __builtin_bit_cast(unsigned, zw);
        u.w = ((unsigned)idx) << 9;
        tbl[(size_t)row * NB + c] = u;
    }
}

// ---------------------------------------------------------------------------
// Kernel 3 (conv): wave = row, lane = channel. Per j:
//   1x16B uniform table load + 1x8B gather; f16 packed theta math
//   (pk_fma/pk_max/pk_mul) + 2x v_dot2_f32_f16 accumulate.
// Pipeline forced with sched_barrier: table 6 ahead (8 slots -- distance 6
// mod 8 never aliases the slot CC(k) reads; the %6 version clobbered it),
// gather 2 ahead (3 slots).
// ---------------------------------------------------------------------------
__global__ __launch_bounds__(256) void conv_kernel(
    const float* __restrict__ dirs,   // (3, 256)
    const uint4* __restrict__ tbl,    // (16384, 50)
    const unsigned short* __restrict__ fo_s, // (16384, 64, 4) f16
    float* __restrict__ out)          // (16384, 64) holds center on entry
{
    const int bid = blockIdx.x;                     // 0..4095
    const int swz = ((bid & 7) << 9) + (bid >> 3);  // XCD bijection on 4096
    const int wv  = threadIdx.x >> 6;
    const int c   = threadIdx.x & 63;
    const int row = swz * 4 + wv;                   // same batch per block
    const int b   = swz >> 10;

    // f16 direction-column pairs: component = support {0,1} / {2,3}
    h16x2 cs01x, cs01y, cs01z, cs23x, cs23y, cs23z;
    {
        float sx[4], sy[4], sz[4];
#pragma unroll
        for (int s = 0; s < 4; ++s) {
            const int col = s * 64 + c;
            const float d0 = dirs[col], d1 = dirs[256 + col], d2 = dirs[512 + col];
            const float inv = 1.f / fmaxf(sqrtf(d0 * d0 + d1 * d1 + d2 * d2), 1e-12f);
            sx[s] = d0 * inv; sy[s] = d1 * inv; sz[s] = d2 * inv;
        }
        cs01x = (h16x2){ (_Float16)sx[0], (_Float16)sx[1] };
        cs01y = (h16x2){ (_Float16)sy[0], (_Float16)sy[1] };
        cs01z = (h16x2){ (_Float16)sz[0], (_Float16)sz[1] };
        cs23x = (h16x2){ (_Float16)sx[2], (_Float16)sx[3] };
        cs23y = (h16x2){ (_Float16)sy[2], (_Float16)sy[3] };
        cs23z = (h16x2){ (_Float16)sz[2], (_Float16)sz[3] };
    }

    const float center = out[(size_t)row * OC + c];

    const char* baseb = (const char*)fo_s + (size_t)b * ((size_t)V * OC * SUP * 2);
    const unsigned c8 = (unsigned)(c << 3);
    const uint4* __restrict__ trow = tbl + (size_t)row * NB;

    uint4 th[8];
    uint2 g[3];
    float acc0 = 0.f, acc1 = 0.f;
    const h16x2 hz = { (_Float16)0.f, (_Float16)0.f };

#define LT(k) { th[(k) % 8] = trow[(k)]; }
#define LG(k) { g[(k) % 3] = *reinterpret_cast<const uint2*>(baseb + (size_t)(th[(k) % 8].w + c8)); }
#define CC(k) { \
        const uint4 t = th[(k) % 8]; \
        const h16x2 dxdx = __builtin_bit_cast(h16x2, t.x); \
        const h16x2 dydy = __builtin_bit_cast(h16x2, t.y); \
        const unsigned zlo = t.z & 0xffffu, zhi = t.z >> 16; \
        const h16x2 dzdz = __builtin_bit_cast(h16x2, zlo | (zlo << 16)); \
        const h16x2 wjwj = __builtin_bit_cast(h16x2, zhi | (zhi << 16)); \
        h16x2 t01 = dxdx * cs01x + dydy * cs01y + dzdz * cs01z; \
        h16x2 t23 = dxdx * cs23x + dydy * cs23y + dzdz * cs23z; \
        t01 = __builtin_elementwise_max(t01, hz); \
        t23 = __builtin_elementwise_max(t23, hz); \
        t01 *= wjwj; t23 *= wjwj; \
        const uint2 gg = g[(k) % 3]; \
        acc0 = fdot2acc(t01, __builtin_bit_cast(h16x2, gg.x), acc0); \
        acc1 = fdot2acc(t23, __builtin_bit_cast(h16x2, gg.y), acc1); }

    LT(0); LT(1); LT(2); LT(3); LT(4); LT(5);
    LG(0); LG(1);
#pragma unroll
    for (int k = 0; k < NB; ++k) {
        if (k + 6 < NB) LT(k + 6);
        __builtin_amdgcn_sched_barrier(0);
        CC(k);
        __builtin_amdgcn_sched_barrier(0);
        if (k + 2 < NB) LG(k + 2);
    }
#undef LT
#undef LG
#undef CC

    out[(size_t)row * OC + c] = center + acc0 + acc1;
}

// ---------------------------------------------------------------------------
extern "C" void kernel_launch(void* const* d_in, const int* in_sizes, int n_in,
                              void* d_out, int out_size, void* d_ws, size_t ws_size,
                              hipStream_t stream) {
    const int*   nidx  = (const int*)  d_in[0];
    const float* verts = (const float*)d_in[1];
    const float* fm    = (const float*)d_in[2];
    const float* nval  = (const float*)d_in[3];
    const float* W     = (const float*)d_in[4];
    const float* bias  = (const float*)d_in[5];
    const float* dirs  = (const float*)d_in[6];
    float*       out   = (float*)d_out;

    // ws: fo_s 8 MiB | tbl 12.5 MiB  (20.5 MiB total)
    unsigned short* fo_s = (unsigned short*)d_ws;
    uint4*          tbl  = (uint4*)((char*)d_ws + 8388608);

    feat_kernel<<<(BS * V) / 64, 256, 0, stream>>>(fm, W, bias, out, fo_s);
    prep_kernel<<<(BS * V) / 4, 256, 0, stream>>>(nidx, verts, nval, tbl);
    conv_kernel<<<(BS * V) / 4, 256, 0, stream>>>(dirs, tbl, fo_s, out);
}

// Round 12
// 52.252 us; speedup vs baseline: 2.1111x; 2.1111x over previous
//
#include <hip/hip_runtime.h>
#include <math.h>

#define BS   4
#define V    4096
#define NB   50
#define IC   64
#define OC   64
#define SUP  4
#define WCOL 320
#define WT_STRIDE 72     // shorts; 144B row -> 2-way LDS bank aliasing (free)

typedef float    f32x4 __attribute__((ext_vector_type(4)));
typedef short    s16x8 __attribute__((ext_vector_type(8)));
typedef _Float16 h16x2 __attribute__((ext_vector_type(2)));

__device__ inline unsigned short bf16r(float f) {          // RNE f32->bf16
    unsigned u = __builtin_bit_cast(unsigned, f);
    u += 0x7FFFu + ((u >> 16) & 1u);
    return (unsigned short)(u >> 16);
}
__device__ inline unsigned short f16b(float f) {           // f32->f16 bits
    return __builtin_bit_cast(unsigned short, (_Float16)f);
}
__device__ inline float fdot2acc(h16x2 a, h16x2 b, float c) {
#if __has_builtin(__builtin_amdgcn_fdot2)
    return __builtin_amdgcn_fdot2(a, b, c, false);   // v_dot2_f32_f16
#else
    return c + (float)a.x * (float)b.x + (float)a.y * (float)b.y;
#endif
}

// ---------------------------------------------------------------------------
// Kernel 1 (MFMA): feature_out = fm @ W + bias.
//   out[row*64 + c]          = feature_out[row][c]          (center -> d_out)
//   fo_s[(row*64 + c)*4 + s] = f16(feature_out[row][64+s*64+c])
// ---------------------------------------------------------------------------
__global__ __launch_bounds__(256) void feat_kernel(
    const float* __restrict__ fm,    // (16384, 64)
    const float* __restrict__ W,     // (64, 320)
    const float* __restrict__ bias,  // (320,)
    float* __restrict__ out,         // (16384, 64)  center slice
    unsigned short* __restrict__ fo_s)  // f16
{
    __shared__ unsigned short wt[WCOL * WT_STRIDE];  // wt[col][k], 45 KB
    const int t = threadIdx.x;

#pragma unroll
    for (int i = 0; i < 20; ++i) {
        const int idx4 = t + i * 256;
        const int e    = idx4 * 4;
        const int k    = e / WCOL;
        const int col  = e - k * WCOL;
        const float4 v = reinterpret_cast<const float4*>(W)[idx4];
        wt[(col + 0) * WT_STRIDE + k] = bf16r(v.x);
        wt[(col + 1) * WT_STRIDE + k] = bf16r(v.y);
        wt[(col + 2) * WT_STRIDE + k] = bf16r(v.z);
        wt[(col + 3) * WT_STRIDE + k] = bf16r(v.w);
    }
    __syncthreads();

    const int w   = t >> 6;
    const int l   = t & 63;
    const int rlo = l & 15;
    const int kg  = l >> 4;
    const int row = blockIdx.x * 64 + w * 16 + rlo;

    const float* fr = &fm[row * IC + kg * 8];
    s16x8 a0, a1;
#pragma unroll
    for (int e = 0; e < 8; ++e) {
        a0[e] = (short)bf16r(fr[e]);
        a1[e] = (short)bf16r(fr[32 + e]);
    }

    const int drow0 = blockIdx.x * 64 + w * 16 + kg * 4;
#pragma unroll
    for (int ct = 0; ct < 20; ++ct) {
        const int col = ct * 16 + rlo;
        const s16x8 b0 = *reinterpret_cast<const s16x8*>(&wt[col * WT_STRIDE + kg * 8]);
        const s16x8 b1 = *reinterpret_cast<const s16x8*>(&wt[col * WT_STRIDE + 32 + kg * 8]);
        f32x4 acc = {0.f, 0.f, 0.f, 0.f};
        acc = __builtin_amdgcn_mfma_f32_16x16x32_bf16(a0, b0, acc, 0, 0, 0);
        acc = __builtin_amdgcn_mfma_f32_16x16x32_bf16(a1, b1, acc, 0, 0, 0);
        const float bv = bias[col];
        if (ct < 4) {
#pragma unroll
            for (int r = 0; r < 4; ++r)
                out[(drow0 + r) * OC + col] = acc[r] + bv;
        } else {
            const int cc = (col - OC) & 63;
            const int s  = (col - OC) >> 6;
#pragma unroll
            for (int r = 0; r < 4; ++r)
                fo_s[((drow0 + r) * OC + cc) * SUP + s] =
                    __builtin_bit_cast(unsigned short, (_Float16)(acc[r] + bv));
        }
    }
}

// ---------------------------------------------------------------------------
// Kernel 2 (conv): wave = 2 rows, lane = channel. The per-(row,j) uniform
// data lives IN REGISTERS spread across lanes (lane ll holds entry j=ll),
// fetched per-iteration with v_readlane -> SGPRs (zero memory latency).
// Only in-loop memory op: the 8B coalesced gather. Address stream is
// register-computable -> compiler can run gathers arbitrarily far ahead.
// ---------------------------------------------------------------------------
__global__ __launch_bounds__(256) void conv_kernel(
    const int*   __restrict__ nidx,   // (BS, V, 50)
    const float* __restrict__ verts,  // (BS, V, 3)
    const float* __restrict__ nval,   // (BS, V, 50)
    const float* __restrict__ dirs,   // (3, 256)
    const unsigned short* __restrict__ fo_s, // (16384, 64, 4) f16
    float* __restrict__ out)          // (16384, 64) holds center on entry
{
    const int bid  = blockIdx.x;                     // 0..2047
    const int swz  = ((bid & 7) << 8) + (bid >> 3);  // XCD bijection on 2048
    const int wv   = threadIdx.x >> 6;
    const int l    = threadIdx.x & 63;               // lane = channel
    const int row0 = swz * 8 + wv * 2;
    const int row1 = row0 + 1;
    const int b    = row0 >> 12;                     // same batch for row1

    // f16 direction-column pairs: component = support {0,1} / {2,3}
    h16x2 cs01x, cs01y, cs01z, cs23x, cs23y, cs23z;
    {
        float sx[4], sy[4], sz[4];
#pragma unroll
        for (int s = 0; s < 4; ++s) {
            const int col = s * 64 + l;
            const float d0 = dirs[col], d1 = dirs[256 + col], d2 = dirs[512 + col];
            const float inv = 1.f / fmaxf(sqrtf(d0 * d0 + d1 * d1 + d2 * d2), 1e-12f);
            sx[s] = d0 * inv; sy[s] = d1 * inv; sz[s] = d2 * inv;
        }
        cs01x = (h16x2){ (_Float16)sx[0], (_Float16)sx[1] };
        cs01y = (h16x2){ (_Float16)sy[0], (_Float16)sy[1] };
        cs01z = (h16x2){ (_Float16)sz[0], (_Float16)sz[1] };
        cs23x = (h16x2){ (_Float16)sx[2], (_Float16)sx[3] };
        cs23y = (h16x2){ (_Float16)sy[2], (_Float16)sy[3] };
        cs23z = (h16x2){ (_Float16)sz[2], (_Float16)sz[3] };
    }

    // --- per-row setup: lane ll<50 builds packed entry for j=ll -----------
    unsigned ex0, ey0, ez0, eo0, ex1, ey1, ez1, eo1;
    {
        auto setup = [&](int row, unsigned& ux, unsigned& uy,
                         unsigned& uz, unsigned& uo) {
            const float nv = (l < NB) ? nval[(size_t)row * NB + l] : 0.f;
            float ss = nv * nv;
#pragma unroll
            for (int o = 32; o > 0; o >>= 1) ss += __shfl_xor(ss, o);
            const float wn = nv * (1.f / fmaxf(sqrtf(ss), 1e-12f));
            ux = uy = uz = uo = 0u;
            if (l < NB) {
                const int idx = nidx[(size_t)row * NB + l];
                const float* vn = &verts[(size_t)(b * V + idx) * 3];
                const float* vc = &verts[(size_t)row * 3];
                float dx = vn[0] - vc[0], dy = vn[1] - vc[1], dz = vn[2] - vc[2];
                const float inv = 1.f / fmaxf(sqrtf(dx*dx + dy*dy + dz*dz), 1e-12f);
                dx *= inv; dy *= inv; dz *= inv;
                const unsigned hx = f16b(dx), hy = f16b(dy);
                const unsigned hzv = f16b(dz), hw = f16b(wn);
                ux = hx | (hx << 16);
                uy = hy | (hy << 16);
                uz = hzv | (hw << 16);
                uo = ((unsigned)idx) << 9;
            }
        };
        setup(row0, ex0, ey0, ez0, eo0);
        setup(row1, ex1, ey1, ez1, eo1);
    }

    const float ctr0 = out[(size_t)row0 * OC + l];
    const float ctr1 = out[(size_t)row1 * OC + l];

    const char* baseb = (const char*)fo_s + (size_t)b * ((size_t)V * OC * SUP * 2);
    const unsigned c8 = (unsigned)(l << 3);

    float a00 = 0.f, a01 = 0.f, a10 = 0.f, a11 = 0.f;
    const h16x2 hz = { (_Float16)0.f, (_Float16)0.f };

#define ROWOP(EX, EY, EZ, EO, A0, A1) { \
        const unsigned ax = (unsigned)__builtin_amdgcn_readlane((int)(EX), j); \
        const unsigned ay = (unsigned)__builtin_amdgcn_readlane((int)(EY), j); \
        const unsigned az = (unsigned)__builtin_amdgcn_readlane((int)(EZ), j); \
        const unsigned ao = (unsigned)__builtin_amdgcn_readlane((int)(EO), j); \
        const h16x2 dxdx = __builtin_bit_cast(h16x2, ax); \
        const h16x2 dydy = __builtin_bit_cast(h16x2, ay); \
        const unsigned zlo = az & 0xffffu, zhi = az >> 16; \
        const h16x2 dzdz = __builtin_bit_cast(h16x2, zlo | (zlo << 16)); \
        const h16x2 wjwj = __builtin_bit_cast(h16x2, zhi | (zhi << 16)); \
        h16x2 t01 = dxdx * cs01x + dydy * cs01y + dzdz * cs01z; \
        h16x2 t23 = dxdx * cs23x + dydy * cs23y + dzdz * cs23z; \
        t01 = __builtin_elementwise_max(t01, hz); \
        t23 = __builtin_elementwise_max(t23, hz); \
        t01 *= wjwj; t23 *= wjwj; \
        const uint2 gg = *reinterpret_cast<const uint2*>(baseb + (size_t)(ao + c8)); \
        A0 = fdot2acc(t01, __builtin_bit_cast(h16x2, gg.x), A0); \
        A1 = fdot2acc(t23, __builtin_bit_cast(h16x2, gg.y), A1); }

#pragma unroll
    for (int j = 0; j < NB; ++j) {
        ROWOP(ex0, ey0, ez0, eo0, a00, a01)
        ROWOP(ex1, ey1, ez1, eo1, a10, a11)
    }
#undef ROWOP

    out[(size_t)row0 * OC + l] = ctr0 + a00 + a01;
    out[(size_t)row1 * OC + l] = ctr1 + a10 + a11;
}

// ---------------------------------------------------------------------------
extern "C" void kernel_launch(void* const* d_in, const int* in_sizes, int n_in,
                              void* d_out, int out_size, void* d_ws, size_t ws_size,
                              hipStream_t stream) {
    const int*   nidx  = (const int*)  d_in[0];
    const float* verts = (const float*)d_in[1];
    const float* fm    = (const float*)d_in[2];
    const float* nval  = (const float*)d_in[3];
    const float* W     = (const float*)d_in[4];
    const float* bias  = (const float*)d_in[5];
    const float* dirs  = (const float*)d_in[6];
    float*       out   = (float*)d_out;

    unsigned short* fo_s = (unsigned short*)d_ws;     // 8 MiB

    feat_kernel<<<(BS * V) / 64, 256, 0, stream>>>(fm, W, bias, out, fo_s);
    conv_kernel<<<(BS * V) / 8, 256, 0, stream>>>(nidx, verts, nval, dirs,
                                                  fo_s, out);
}